// Round 7
// baseline (382.757 us; speedup 1.0000x reference)
//
#include <hip/hip_runtime.h>
#include <hip/hip_fp16.h>
#include <math.h>

#define NN 50000
#define NE 800000
#define KDIM 128
#define NB 196            // dst buckets of 256 nodes: bucket = dst >> 8
#define CPAD 16           // pad atomic counters to one per 64B line

// ---------------- GEMM: Y[nrows x 128] @ W[128 x OUT] -> fp16 Y ----------------
constexpr int BM = 64, BN = 128, KC = 32;

__global__ __launch_bounds__(256) void gemm_kernel(
    const float* __restrict__ X, const float* __restrict__ W,
    __half* __restrict__ Y, int nrows, int OUT) {
  __shared__ __align__(16) float XsT[KC][BM + 4];
  __shared__ __align__(16) float Ws[KC][BN + 4];
  const int tid = threadIdx.x;
  const int row0 = blockIdx.x * BM;
  const int c  = tid & 15;
  const int rg = tid >> 4;

  float acc[4][8];
#pragma unroll
  for (int i = 0; i < 4; i++)
#pragma unroll
    for (int j = 0; j < 8; j++) acc[i][j] = 0.f;

  const int lr  = tid >> 2;
  const int lq  = tid & 3;
  const int wk  = tid >> 3;
  const int ws0 = tid & 7;

  for (int k0 = 0; k0 < KDIM; k0 += KC) {
#pragma unroll
    for (int i = 0; i < 2; i++) {
      int slot = lq + i * 4;
      int kk = slot * 4;
      float4 v = make_float4(0.f, 0.f, 0.f, 0.f);
      int grow = row0 + lr;
      if (grow < nrows) v = *(const float4*)&X[(size_t)grow * KDIM + k0 + kk];
      XsT[kk + 0][lr] = v.x; XsT[kk + 1][lr] = v.y;
      XsT[kk + 2][lr] = v.z; XsT[kk + 3][lr] = v.w;
    }
#pragma unroll
    for (int i = 0; i < 4; i++) {
      int slot = ws0 + i * 8;
      int col4 = slot * 4;
      float4 v = make_float4(0.f, 0.f, 0.f, 0.f);
      if (col4 < OUT) v = *(const float4*)&W[(size_t)(k0 + wk) * OUT + col4];
      *(float4*)&Ws[wk][col4] = v;
    }
    __syncthreads();
#pragma unroll
    for (int k = 0; k < KC; ++k) {
      float4 a  = *(const float4*)&XsT[k][rg * 4];
      float4 p0 = *(const float4*)&Ws[k][c * 4];
      float4 p1 = *(const float4*)&Ws[k][c * 4 + 64];
      float av[4] = {a.x, a.y, a.z, a.w};
      float bv[8] = {p0.x, p0.y, p0.z, p0.w, p1.x, p1.y, p1.z, p1.w};
#pragma unroll
      for (int i = 0; i < 4; i++)
#pragma unroll
        for (int j = 0; j < 8; j++) acc[i][j] = fmaf(av[i], bv[j], acc[i][j]);
    }
    __syncthreads();
  }
#pragma unroll
  for (int i = 0; i < 4; i++) {
    int grow = row0 + rg * 4 + i;
    if (grow >= nrows) continue;
    __half2 h01 = __floats2half2_rn(acc[i][0], acc[i][1]);
    __half2 h23 = __floats2half2_rn(acc[i][2], acc[i][3]);
    *(__half2*)&Y[(size_t)grow * OUT + c * 4 + 0] = h01;
    *(__half2*)&Y[(size_t)grow * OUT + c * 4 + 2] = h23;
    if (64 + c * 4 < OUT) {
      __half2 h45 = __floats2half2_rn(acc[i][4], acc[i][5]);
      __half2 h67 = __floats2half2_rn(acc[i][6], acc[i][7]);
      *(__half2*)&Y[(size_t)grow * OUT + 64 + c * 4 + 0] = h45;
      *(__half2*)&Y[(size_t)grow * OUT + 64 + c * 4 + 2] = h67;
    }
  }
}

// ---------------- mean aggregation (+bias, +optional LN+ReLU) -----------
template <int F, bool LN>
__global__ __launch_bounds__(256) void agg_kernel(
    const __half* __restrict__ ft,
    const int* __restrict__ row_ptr, const int* __restrict__ es,
    const float* __restrict__ bias, const float* __restrict__ g,
    const float* __restrict__ beta, float* __restrict__ out, int n) {
  int gw = (blockIdx.x * blockDim.x + threadIdx.x) >> 6;
  int lane = threadIdx.x & 63;
  if (gw >= n) return;
  int b = row_ptr[gw], e = row_ptr[gw + 1];
  int deg = e - b;

  constexpr int LPR = F / 8;      // lanes per row (8 halves = 16B each)
  constexpr int EW  = 64 / LPR;   // edges in flight
  const int sub = lane / LPR;
  const int ll  = lane % LPR;
  float acc[8];
#pragma unroll
  for (int q = 0; q < 8; q++) acc[q] = 0.f;

  for (int cb = b; cb < e; cb += 64) {
    int rem = e - cb; if (rem > 64) rem = 64;
    int sn_l = 0;
    if (lane < rem) sn_l = es[cb + lane];
    for (int j = 0; j < rem; j += EW) {
      int jj = j + sub;
      int sn = __shfl(sn_l, jj, 64);
      if (jj < rem) {
        union { float4 f4; __half2 h2[4]; } u;
        u.f4 = *(const float4*)&ft[(size_t)sn * F + ll * 8];
#pragma unroll
        for (int q = 0; q < 4; q++) {
          float2 f = __half22float2(u.h2[q]);
          acc[2 * q + 0] += f.x;
          acc[2 * q + 1] += f.y;
        }
      }
    }
  }

#pragma unroll
  for (int o = 32; o >= LPR; o >>= 1)
#pragma unroll
    for (int q = 0; q < 8; q++) acc[q] += __shfl_xor(acc[q], o, 64);

  float sc = (deg > 0) ? (1.0f / (float)deg) : 0.f;
  float4 b4a = *(const float4*)&bias[ll * 8 + 0];
  float4 b4b = *(const float4*)&bias[ll * 8 + 4];
  acc[0] = fmaf(acc[0], sc, b4a.x); acc[1] = fmaf(acc[1], sc, b4a.y);
  acc[2] = fmaf(acc[2], sc, b4a.z); acc[3] = fmaf(acc[3], sc, b4a.w);
  acc[4] = fmaf(acc[4], sc, b4b.x); acc[5] = fmaf(acc[5], sc, b4b.y);
  acc[6] = fmaf(acc[6], sc, b4b.z); acc[7] = fmaf(acc[7], sc, b4b.w);

  if (LN) {
    float sum = 0.f;
#pragma unroll
    for (int q = 0; q < 8; q++) sum += acc[q];
#pragma unroll
    for (int o = LPR / 2; o > 0; o >>= 1) sum += __shfl_xor(sum, o, 64);
    float mean = sum * (1.0f / 128.0f);
    float var = 0.f;
#pragma unroll
    for (int q = 0; q < 8; q++) { acc[q] -= mean; var = fmaf(acc[q], acc[q], var); }
#pragma unroll
    for (int o = LPR / 2; o > 0; o >>= 1) var += __shfl_xor(var, o, 64);
    float r = rsqrtf(var * (1.0f / 128.0f) + 1e-5f);
    float4 g4a = *(const float4*)&g[ll * 8 + 0];
    float4 g4b = *(const float4*)&g[ll * 8 + 4];
    float4 be4a = *(const float4*)&beta[ll * 8 + 0];
    float4 be4b = *(const float4*)&beta[ll * 8 + 4];
    float4 r0, r1;
    r0.x = fmaxf(acc[0] * r * g4a.x + be4a.x, 0.f);
    r0.y = fmaxf(acc[1] * r * g4a.y + be4a.y, 0.f);
    r0.z = fmaxf(acc[2] * r * g4a.z + be4a.z, 0.f);
    r0.w = fmaxf(acc[3] * r * g4a.w + be4a.w, 0.f);
    r1.x = fmaxf(acc[4] * r * g4b.x + be4b.x, 0.f);
    r1.y = fmaxf(acc[5] * r * g4b.y + be4b.y, 0.f);
    r1.z = fmaxf(acc[6] * r * g4b.z + be4b.z, 0.f);
    r1.w = fmaxf(acc[7] * r * g4b.w + be4b.w, 0.f);
    if (sub == 0) {
      *(float4*)&out[(size_t)gw * F + ll * 8 + 0] = r0;
      *(float4*)&out[(size_t)gw * F + ll * 8 + 4] = r1;
    }
  } else {
    if (sub == 0) {
      *(float4*)&out[(size_t)gw * F + ll * 8 + 0] = make_float4(acc[0], acc[1], acc[2], acc[3]);
      *(float4*)&out[(size_t)gw * F + ll * 8 + 4] = make_float4(acc[4], acc[5], acc[6], acc[7]);
    }
  }
}

// ---------------- bucketed CSR build (by dst; bucket = dst>>8, 196 buckets x 256 nodes) --------
// Stage 1: per-bucket histogram (LDS, then one global atomic per block x bucket)
__global__ __launch_bounds__(256) void bhist_kernel(const int* __restrict__ dst,
                                                    int* __restrict__ bhist) {
  __shared__ int hh[256];
  int tid = threadIdx.x;
  hh[tid] = 0;
  __syncthreads();
  int base = (blockIdx.x * 256 + tid) * 4;
  if (base + 3 < NE) {
    int4 d = *(const int4*)&dst[base];
    atomicAdd(&hh[d.x >> 8], 1);
    atomicAdd(&hh[d.y >> 8], 1);
    atomicAdd(&hh[d.z >> 8], 1);
    atomicAdd(&hh[d.w >> 8], 1);
  } else {
#pragma unroll
    for (int k = 0; k < 4; k++)
      if (base + k < NE) atomicAdd(&hh[dst[base + k] >> 8], 1);
  }
  __syncthreads();
  if (tid < NB && hh[tid]) atomicAdd(&bhist[tid * CPAD], hh[tid]);
}

// Stage 2: scan the 196 bucket totals (single block)
__global__ __launch_bounds__(256) void bscan_kernel(const int* __restrict__ bhist,
                                                    int* __restrict__ bucket_base,
                                                    int* __restrict__ bfill) {
  int tid = threadIdx.x;
  int lane = tid & 63, wid = tid >> 6;
  int v = (tid < NB) ? bhist[tid * CPAD] : 0;
  int x = v;
#pragma unroll
  for (int o = 1; o < 64; o <<= 1) {
    int y = __shfl_up(x, o, 64);
    if (lane >= o) x += y;
  }
  __shared__ int wsum[4];
  if (lane == 63) wsum[wid] = x;
  __syncthreads();
  int wpre = 0;
  for (int w = 0; w < wid; w++) wpre += wsum[w];
  int excl = wpre + x - v;
  if (tid < NB) {
    bucket_base[tid] = excl;
    bfill[tid * CPAD] = excl;
  }
  if (tid == 0) bucket_base[NB] = NE;
}

// Stage 3: scatter (src,dst) into bucket-contiguous staging order
__global__ __launch_bounds__(256) void stage_kernel(const int* __restrict__ src,
                                                    const int* __restrict__ dst,
                                                    int* __restrict__ bfill,
                                                    int2* __restrict__ staged) {
  int e = blockIdx.x * blockDim.x + threadIdx.x;
  if (e < NE) {
    int d = dst[e];
    int pos = atomicAdd(&bfill[(d >> 8) * CPAD], 1);
    staged[pos] = make_int2(src[e], d);
  }
}

// Stage 4: one block per bucket -> LDS per-dst hist + scan -> row_ptr + es (all writes local)
__global__ __launch_bounds__(256) void bucket_csr_kernel(const int2* __restrict__ staged,
                                                         const int* __restrict__ bucket_base,
                                                         int* __restrict__ row_ptr,
                                                         int* __restrict__ es) {
  int b = blockIdx.x;
  int tid = threadIdx.x;
  int lo = bucket_base[b], hi = bucket_base[b + 1];
  int dbase = b << 8;
  __shared__ int cnt[256];
  __shared__ int fill_l[256];
  __shared__ int wsum[4];
  cnt[tid] = 0;
  __syncthreads();
  for (int i = lo + tid; i < hi; i += 256)
    atomicAdd(&cnt[staged[i].y - dbase], 1);
  __syncthreads();
  int v = cnt[tid];
  int lane = tid & 63, wid = tid >> 6;
  int x = v;
#pragma unroll
  for (int o = 1; o < 64; o <<= 1) {
    int y = __shfl_up(x, o, 64);
    if (lane >= o) x += y;
  }
  if (lane == 63) wsum[wid] = x;
  __syncthreads();
  int wpre = 0;
  for (int w = 0; w < wid; w++) wpre += wsum[w];
  int start = lo + wpre + x - v;   // absolute exclusive prefix
  int node = dbase + tid;
  if (node < NN) row_ptr[node] = start;
  fill_l[tid] = start;
  __syncthreads();
  for (int i = lo + tid; i < hi; i += 256) {
    int2 ed = staged[i];
    int pos = atomicAdd(&fill_l[ed.y - dbase], 1);
    es[pos] = ed.x;
  }
  if (b == 0 && tid == 0) row_ptr[NN] = NE;
}

// ---------------- orchestration ----------------
extern "C" void kernel_launch(void* const* d_in, const int* in_sizes, int n_in,
                              void* d_out, int out_size, void* d_ws, size_t ws_size,
                              hipStream_t stream) {
  (void)in_sizes; (void)n_in; (void)out_size; (void)ws_size;
  const float* feat = (const float*)d_in[0];
  const int* src = (const int*)d_in[1];
  const int* dst = (const int*)d_in[2];
  const float* W0 = (const float*)d_in[3];
  const float* b0 = (const float*)d_in[4];
  const float* W1 = (const float*)d_in[5];
  const float* b1 = (const float*)d_in[6];
  const float* W2 = (const float*)d_in[7];
  const float* b2 = (const float*)d_in[8];
  const float* ln1g = (const float*)d_in[9];
  const float* ln1b = (const float*)d_in[10];
  const float* ln2g = (const float*)d_in[11];
  const float* ln2b = (const float*)d_in[12];
  float* out = (float*)d_out;

  char* p = (char*)d_ws;
  auto alloc = [&](size_t bytes) {
    char* r = p;
    p += (bytes + 255) & ~size_t(255);
    return r;
  };
  __half* fth      = (__half*)alloc((size_t)NN * 128 * 2);
  float* h         = (float*)alloc((size_t)NN * 128 * 4);
  int* row_ptr     = (int*)alloc((size_t)(NN + 1) * 4);
  int* es          = (int*)alloc((size_t)NE * 4);
  int2* staged     = (int2*)alloc((size_t)NE * 8);
  int* bhist       = (int*)alloc((size_t)NB * CPAD * 4);
  int* bfill       = (int*)alloc((size_t)NB * CPAD * 4);
  int* bucket_base = (int*)alloc((size_t)(NB + 1) * 4);

  // CSR by dst (graph identical for all 3 convs), locality-bucketed build
  hipMemsetAsync(bhist, 0, (size_t)NB * CPAD * 4, stream);
  int hb = (NE + 1023) / 1024;   // 4 edges per thread
  bhist_kernel<<<hb, 256, 0, stream>>>(dst, bhist);
  bscan_kernel<<<1, 256, 0, stream>>>(bhist, bucket_base, bfill);
  int eb = (NE + 255) / 256;
  stage_kernel<<<eb, 256, 0, stream>>>(src, dst, bfill, staged);
  bucket_csr_kernel<<<NB, 256, 0, stream>>>(staged, bucket_base, row_ptr, es);

  int gb = (NN + BM - 1) / BM;
  int nwb = (NN + 3) / 4;

  gemm_kernel<<<gb, 256, 0, stream>>>(feat, W0, fth, NN, 128);
  agg_kernel<128, true><<<nwb, 256, 0, stream>>>(fth, row_ptr, es, b0, ln1g, ln1b, h, NN);
  gemm_kernel<<<gb, 256, 0, stream>>>(h, W1, fth, NN, 128);
  agg_kernel<128, true><<<nwb, 256, 0, stream>>>(fth, row_ptr, es, b1, ln2g, ln2b, h, NN);
  gemm_kernel<<<gb, 256, 0, stream>>>(h, W2, fth, NN, 64);
  agg_kernel<64, false><<<nwb, 256, 0, stream>>>(fth, row_ptr, es, b2, nullptr, nullptr, out, NN);
}

// Round 8
// 299.745 us; speedup vs baseline: 1.2769x; 1.2769x over previous
//
#include <hip/hip_runtime.h>
#include <hip/hip_fp16.h>
#include <math.h>

#define NN 50000
#define NE 800000
#define KDIM 128
#define NB 196            // dst buckets of 256 nodes: bucket = dst >> 8
#define CPAD 16           // pad global atomic counters to one per 64B line
#define STILE 4096        // edges per stage block

// ---------------- GEMM: Y[nrows x 128] @ W[128 x OUT] -> fp16 Y ----------------
constexpr int BM = 64, BN = 128, KC = 32;

__global__ __launch_bounds__(256) void gemm_kernel(
    const float* __restrict__ X, const float* __restrict__ W,
    __half* __restrict__ Y, int nrows, int OUT) {
  __shared__ __align__(16) float XsT[KC][BM + 4];
  __shared__ __align__(16) float Ws[KC][BN + 4];
  const int tid = threadIdx.x;
  const int row0 = blockIdx.x * BM;
  const int c  = tid & 15;
  const int rg = tid >> 4;

  float acc[4][8];
#pragma unroll
  for (int i = 0; i < 4; i++)
#pragma unroll
    for (int j = 0; j < 8; j++) acc[i][j] = 0.f;

  const int lr  = tid >> 2;
  const int lq  = tid & 3;
  const int wk  = tid >> 3;
  const int ws0 = tid & 7;

  for (int k0 = 0; k0 < KDIM; k0 += KC) {
#pragma unroll
    for (int i = 0; i < 2; i++) {
      int slot = lq + i * 4;
      int kk = slot * 4;
      float4 v = make_float4(0.f, 0.f, 0.f, 0.f);
      int grow = row0 + lr;
      if (grow < nrows) v = *(const float4*)&X[(size_t)grow * KDIM + k0 + kk];
      XsT[kk + 0][lr] = v.x; XsT[kk + 1][lr] = v.y;
      XsT[kk + 2][lr] = v.z; XsT[kk + 3][lr] = v.w;
    }
#pragma unroll
    for (int i = 0; i < 4; i++) {
      int slot = ws0 + i * 8;
      int col4 = slot * 4;
      float4 v = make_float4(0.f, 0.f, 0.f, 0.f);
      if (col4 < OUT) v = *(const float4*)&W[(size_t)(k0 + wk) * OUT + col4];
      *(float4*)&Ws[wk][col4] = v;
    }
    __syncthreads();
#pragma unroll
    for (int k = 0; k < KC; ++k) {
      float4 a  = *(const float4*)&XsT[k][rg * 4];
      float4 p0 = *(const float4*)&Ws[k][c * 4];
      float4 p1 = *(const float4*)&Ws[k][c * 4 + 64];
      float av[4] = {a.x, a.y, a.z, a.w};
      float bv[8] = {p0.x, p0.y, p0.z, p0.w, p1.x, p1.y, p1.z, p1.w};
#pragma unroll
      for (int i = 0; i < 4; i++)
#pragma unroll
        for (int j = 0; j < 8; j++) acc[i][j] = fmaf(av[i], bv[j], acc[i][j]);
    }
    __syncthreads();
  }
#pragma unroll
  for (int i = 0; i < 4; i++) {
    int grow = row0 + rg * 4 + i;
    if (grow >= nrows) continue;
    __half2 h01 = __floats2half2_rn(acc[i][0], acc[i][1]);
    __half2 h23 = __floats2half2_rn(acc[i][2], acc[i][3]);
    *(__half2*)&Y[(size_t)grow * OUT + c * 4 + 0] = h01;
    *(__half2*)&Y[(size_t)grow * OUT + c * 4 + 2] = h23;
    if (64 + c * 4 < OUT) {
      __half2 h45 = __floats2half2_rn(acc[i][4], acc[i][5]);
      __half2 h67 = __floats2half2_rn(acc[i][6], acc[i][7]);
      *(__half2*)&Y[(size_t)grow * OUT + 64 + c * 4 + 0] = h45;
      *(__half2*)&Y[(size_t)grow * OUT + 64 + c * 4 + 2] = h67;
    }
  }
}

// ---------------- mean aggregation (+bias, +optional LN+ReLU) -----------
template <int F, bool LN>
__global__ __launch_bounds__(256) void agg_kernel(
    const __half* __restrict__ ft,
    const int* __restrict__ row_ptr, const int* __restrict__ es,
    const float* __restrict__ bias, const float* __restrict__ g,
    const float* __restrict__ beta, float* __restrict__ out, int n) {
  int gw = (blockIdx.x * blockDim.x + threadIdx.x) >> 6;
  int lane = threadIdx.x & 63;
  if (gw >= n) return;
  int b = row_ptr[gw], e = row_ptr[gw + 1];
  int deg = e - b;

  constexpr int LPR = F / 8;      // lanes per row (8 halves = 16B each)
  constexpr int EW  = 64 / LPR;   // edges in flight
  const int sub = lane / LPR;
  const int ll  = lane % LPR;
  float acc[8];
#pragma unroll
  for (int q = 0; q < 8; q++) acc[q] = 0.f;

  for (int cb = b; cb < e; cb += 64) {
    int rem = e - cb; if (rem > 64) rem = 64;
    int sn_l = 0;
    if (lane < rem) sn_l = es[cb + lane];
    for (int j = 0; j < rem; j += EW) {
      int jj = j + sub;
      int sn = __shfl(sn_l, jj, 64);
      if (jj < rem) {
        union { float4 f4; __half2 h2[4]; } u;
        u.f4 = *(const float4*)&ft[(size_t)sn * F + ll * 8];
#pragma unroll
        for (int q = 0; q < 4; q++) {
          float2 f = __half22float2(u.h2[q]);
          acc[2 * q + 0] += f.x;
          acc[2 * q + 1] += f.y;
        }
      }
    }
  }

#pragma unroll
  for (int o = 32; o >= LPR; o >>= 1)
#pragma unroll
    for (int q = 0; q < 8; q++) acc[q] += __shfl_xor(acc[q], o, 64);

  float sc = (deg > 0) ? (1.0f / (float)deg) : 0.f;
  float4 b4a = *(const float4*)&bias[ll * 8 + 0];
  float4 b4b = *(const float4*)&bias[ll * 8 + 4];
  acc[0] = fmaf(acc[0], sc, b4a.x); acc[1] = fmaf(acc[1], sc, b4a.y);
  acc[2] = fmaf(acc[2], sc, b4a.z); acc[3] = fmaf(acc[3], sc, b4a.w);
  acc[4] = fmaf(acc[4], sc, b4b.x); acc[5] = fmaf(acc[5], sc, b4b.y);
  acc[6] = fmaf(acc[6], sc, b4b.z); acc[7] = fmaf(acc[7], sc, b4b.w);

  if (LN) {
    float sum = 0.f;
#pragma unroll
    for (int q = 0; q < 8; q++) sum += acc[q];
#pragma unroll
    for (int o = LPR / 2; o > 0; o >>= 1) sum += __shfl_xor(sum, o, 64);
    float mean = sum * (1.0f / 128.0f);
    float var = 0.f;
#pragma unroll
    for (int q = 0; q < 8; q++) { acc[q] -= mean; var = fmaf(acc[q], acc[q], var); }
#pragma unroll
    for (int o = LPR / 2; o > 0; o >>= 1) var += __shfl_xor(var, o, 64);
    float r = rsqrtf(var * (1.0f / 128.0f) + 1e-5f);
    float4 g4a = *(const float4*)&g[ll * 8 + 0];
    float4 g4b = *(const float4*)&g[ll * 8 + 4];
    float4 be4a = *(const float4*)&beta[ll * 8 + 0];
    float4 be4b = *(const float4*)&beta[ll * 8 + 4];
    float4 r0, r1;
    r0.x = fmaxf(acc[0] * r * g4a.x + be4a.x, 0.f);
    r0.y = fmaxf(acc[1] * r * g4a.y + be4a.y, 0.f);
    r0.z = fmaxf(acc[2] * r * g4a.z + be4a.z, 0.f);
    r0.w = fmaxf(acc[3] * r * g4a.w + be4a.w, 0.f);
    r1.x = fmaxf(acc[4] * r * g4b.x + be4b.x, 0.f);
    r1.y = fmaxf(acc[5] * r * g4b.y + be4b.y, 0.f);
    r1.z = fmaxf(acc[6] * r * g4b.z + be4b.z, 0.f);
    r1.w = fmaxf(acc[7] * r * g4b.w + be4b.w, 0.f);
    if (sub == 0) {
      *(float4*)&out[(size_t)gw * F + ll * 8 + 0] = r0;
      *(float4*)&out[(size_t)gw * F + ll * 8 + 4] = r1;
    }
  } else {
    if (sub == 0) {
      *(float4*)&out[(size_t)gw * F + ll * 8 + 0] = make_float4(acc[0], acc[1], acc[2], acc[3]);
      *(float4*)&out[(size_t)gw * F + ll * 8 + 4] = make_float4(acc[4], acc[5], acc[6], acc[7]);
    }
  }
}

// ---------------- bucketed CSR build v3 ----------------
// staged word = src (bits 0..15) | local_dst (bits 16..23); NN < 65536, bucket = dst>>8.

// Stage 1: per-bucket histogram, 4096 edges/block via int4 loads
__global__ __launch_bounds__(256) void bhist_kernel(const int* __restrict__ dst,
                                                    int* __restrict__ bhist) {
  __shared__ int hh[256];
  int tid = threadIdx.x;
  hh[tid] = 0;
  __syncthreads();
#pragma unroll
  for (int q = 0; q < 4; q++) {
    int base = blockIdx.x * STILE + q * 1024 + tid * 4;
    if (base + 3 < NE) {
      int4 d = *(const int4*)&dst[base];
      atomicAdd(&hh[d.x >> 8], 1);
      atomicAdd(&hh[d.y >> 8], 1);
      atomicAdd(&hh[d.z >> 8], 1);
      atomicAdd(&hh[d.w >> 8], 1);
    } else {
#pragma unroll
      for (int k = 0; k < 4; k++)
        if (base + k < NE) atomicAdd(&hh[dst[base + k] >> 8], 1);
    }
  }
  __syncthreads();
  if (tid < NB && hh[tid]) atomicAdd(&bhist[tid * CPAD], hh[tid]);
}

// Stage 2: scan the 196 bucket totals (single block) -> bucket_base, init bfill
__global__ __launch_bounds__(256) void bscan_kernel(const int* __restrict__ bhist,
                                                    int* __restrict__ bucket_base,
                                                    int* __restrict__ bfill) {
  int tid = threadIdx.x;
  int lane = tid & 63, wid = tid >> 6;
  int v = (tid < NB) ? bhist[tid * CPAD] : 0;
  int x = v;
#pragma unroll
  for (int o = 1; o < 64; o <<= 1) {
    int y = __shfl_up(x, o, 64);
    if (lane >= o) x += y;
  }
  __shared__ int wsum[4];
  if (lane == 63) wsum[wid] = x;
  __syncthreads();
  int wpre = 0;
  for (int w = 0; w < wid; w++) wpre += wsum[w];
  int excl = wpre + x - v;
  if (tid < NB) {
    bucket_base[tid] = excl;
    bfill[tid * CPAD] = excl;
  }
  if (tid == 0) bucket_base[NB] = NE;
}

// Stage 3: block-local radix scatter. Each block owns contiguous per-bucket runs
// (one global atomic per block x bucket), so staged lines are written by a single
// workgroup -> no cross-XCD false sharing. Payload 4B packed.
__global__ __launch_bounds__(256) void stage_kernel(const int* __restrict__ src,
                                                    const int* __restrict__ dst,
                                                    int* __restrict__ bfill,
                                                    int* __restrict__ staged) {
  __shared__ int cnt[256];    // local per-bucket counts
  __shared__ int basep[256];  // reserved global base per bucket
  __shared__ int cur[256];    // running local offset
  int tid = threadIdx.x;
  cnt[tid] = 0;
  cur[tid] = 0;
  __syncthreads();
  // pass 1: count
#pragma unroll
  for (int q = 0; q < 4; q++) {
    int base = blockIdx.x * STILE + q * 1024 + tid * 4;
    if (base + 3 < NE) {
      int4 d = *(const int4*)&dst[base];
      atomicAdd(&cnt[d.x >> 8], 1);
      atomicAdd(&cnt[d.y >> 8], 1);
      atomicAdd(&cnt[d.z >> 8], 1);
      atomicAdd(&cnt[d.w >> 8], 1);
    } else {
#pragma unroll
      for (int k = 0; k < 4; k++)
        if (base + k < NE) atomicAdd(&cnt[dst[base + k] >> 8], 1);
    }
  }
  __syncthreads();
  // reserve contiguous runs
  if (tid < NB) basep[tid] = (cnt[tid] > 0) ? atomicAdd(&bfill[tid * CPAD], cnt[tid]) : 0;
  __syncthreads();
  // pass 2: scatter into this block's private runs
#pragma unroll
  for (int q = 0; q < 4; q++) {
    int base = blockIdx.x * STILE + q * 1024 + tid * 4;
    if (base + 3 < NE) {
      int4 d = *(const int4*)&dst[base];
      int4 s = *(const int4*)&src[base];
      int b0 = d.x >> 8, b1 = d.y >> 8, b2 = d.z >> 8, b3 = d.w >> 8;
      int p0 = atomicAdd(&cur[b0], 1);
      staged[basep[b0] + p0] = s.x | ((d.x & 255) << 16);
      int p1 = atomicAdd(&cur[b1], 1);
      staged[basep[b1] + p1] = s.y | ((d.y & 255) << 16);
      int p2 = atomicAdd(&cur[b2], 1);
      staged[basep[b2] + p2] = s.z | ((d.z & 255) << 16);
      int p3 = atomicAdd(&cur[b3], 1);
      staged[basep[b3] + p3] = s.w | ((d.w & 255) << 16);
    } else {
#pragma unroll
      for (int k = 0; k < 4; k++) {
        if (base + k < NE) {
          int d = dst[base + k], s = src[base + k];
          int bb = d >> 8;
          int pp = atomicAdd(&cur[bb], 1);
          staged[basep[bb] + pp] = s | ((d & 255) << 16);
        }
      }
    }
  }
}

// Stage 4: one block per bucket -> LDS per-dst hist + scan -> row_ptr + es
__global__ __launch_bounds__(256) void bucket_csr_kernel(const int* __restrict__ staged,
                                                         const int* __restrict__ bucket_base,
                                                         int* __restrict__ row_ptr,
                                                         int* __restrict__ es) {
  int b = blockIdx.x;
  int tid = threadIdx.x;
  int lo = bucket_base[b], hi = bucket_base[b + 1];
  __shared__ int cnt[256];
  __shared__ int fill_l[256];
  __shared__ int wsum[4];
  cnt[tid] = 0;
  __syncthreads();
  for (int i = lo + tid; i < hi; i += 256)
    atomicAdd(&cnt[(staged[i] >> 16) & 255], 1);
  __syncthreads();
  int v = cnt[tid];
  int lane = tid & 63, wid = tid >> 6;
  int x = v;
#pragma unroll
  for (int o = 1; o < 64; o <<= 1) {
    int y = __shfl_up(x, o, 64);
    if (lane >= o) x += y;
  }
  if (lane == 63) wsum[wid] = x;
  __syncthreads();
  int wpre = 0;
  for (int w = 0; w < wid; w++) wpre += wsum[w];
  int start = lo + wpre + x - v;   // absolute exclusive prefix
  int node = (b << 8) + tid;
  if (node < NN) row_ptr[node] = start;
  fill_l[tid] = start;
  __syncthreads();
  for (int i = lo + tid; i < hi; i += 256) {
    int w = staged[i];
    int pos = atomicAdd(&fill_l[(w >> 16) & 255], 1);
    es[pos] = w & 0xFFFF;
  }
  if (b == 0 && tid == 0) row_ptr[NN] = NE;
}

// ---------------- orchestration ----------------
extern "C" void kernel_launch(void* const* d_in, const int* in_sizes, int n_in,
                              void* d_out, int out_size, void* d_ws, size_t ws_size,
                              hipStream_t stream) {
  (void)in_sizes; (void)n_in; (void)out_size; (void)ws_size;
  const float* feat = (const float*)d_in[0];
  const int* src = (const int*)d_in[1];
  const int* dst = (const int*)d_in[2];
  const float* W0 = (const float*)d_in[3];
  const float* b0 = (const float*)d_in[4];
  const float* W1 = (const float*)d_in[5];
  const float* b1 = (const float*)d_in[6];
  const float* W2 = (const float*)d_in[7];
  const float* b2 = (const float*)d_in[8];
  const float* ln1g = (const float*)d_in[9];
  const float* ln1b = (const float*)d_in[10];
  const float* ln2g = (const float*)d_in[11];
  const float* ln2b = (const float*)d_in[12];
  float* out = (float*)d_out;

  char* p = (char*)d_ws;
  auto alloc = [&](size_t bytes) {
    char* r = p;
    p += (bytes + 255) & ~size_t(255);
    return r;
  };
  __half* fth      = (__half*)alloc((size_t)NN * 128 * 2);
  float* h         = (float*)alloc((size_t)NN * 128 * 4);
  int* row_ptr     = (int*)alloc((size_t)(NN + 1) * 4);
  int* es          = (int*)alloc((size_t)NE * 4);
  int* staged      = (int*)alloc((size_t)NE * 4);
  int* bhist       = (int*)alloc((size_t)NB * CPAD * 4);
  int* bfill       = (int*)alloc((size_t)NB * CPAD * 4);
  int* bucket_base = (int*)alloc((size_t)(NB + 1) * 4);

  // CSR by dst (graph identical for all 3 convs), block-private radix scatter
  hipMemsetAsync(bhist, 0, (size_t)NB * CPAD * 4, stream);
  int sb = (NE + STILE - 1) / STILE;   // 196 blocks
  bhist_kernel<<<sb, 256, 0, stream>>>(dst, bhist);
  bscan_kernel<<<1, 256, 0, stream>>>(bhist, bucket_base, bfill);
  stage_kernel<<<sb, 256, 0, stream>>>(src, dst, bfill, staged);
  bucket_csr_kernel<<<NB, 256, 0, stream>>>(staged, bucket_base, row_ptr, es);

  int gb = (NN + BM - 1) / BM;
  int nwb = (NN + 3) / 4;

  gemm_kernel<<<gb, 256, 0, stream>>>(feat, W0, fth, NN, 128);
  agg_kernel<128, true><<<nwb, 256, 0, stream>>>(fth, row_ptr, es, b0, ln1g, ln1b, h, NN);
  gemm_kernel<<<gb, 256, 0, stream>>>(h, W1, fth, NN, 128);
  agg_kernel<128, true><<<nwb, 256, 0, stream>>>(fth, row_ptr, es, b1, ln2g, ln2b, h, NN);
  gemm_kernel<<<gb, 256, 0, stream>>>(h, W2, fth, NN, 64);
  agg_kernel<64, false><<<nwb, 256, 0, stream>>>(fth, row_ptr, es, b2, nullptr, nullptr, out, NN);
}

// Round 9
// 256.610 us; speedup vs baseline: 1.4916x; 1.1681x over previous
//
#include <hip/hip_runtime.h>
#include <hip/hip_fp16.h>
#include <math.h>

#define NN 50000
#define NE 800000
#define KDIM 128
#define NB 196            // dst buckets of 256 nodes: bucket = dst >> 8
#define CPAD 16           // pad global atomic counters to one per 64B line
#define STILE 4096        // edges per stage block

typedef _Float16 v8h __attribute__((ext_vector_type(8)));
typedef float v4f __attribute__((ext_vector_type(4)));

// ---------------- convert: feat -> fp16, W0/W1/W2 -> fp16 transposed [n][k] ----------------
#define FEAT_B4 6250   // NN*128/4 float4 chunks / 256 threads
__global__ __launch_bounds__(256) void convert_kernel(
    const float* __restrict__ feat, const float* __restrict__ W0,
    const float* __restrict__ W1, const float* __restrict__ W2,
    __half* __restrict__ feat_h, __half* __restrict__ W0T,
    __half* __restrict__ W1T, __half* __restrict__ W2T) {
  int b = blockIdx.x;
  int tid = threadIdx.x;
  if (b < FEAT_B4) {
    int i = b * 256 + tid;
    if (i < NN * 32) {
      float4 v = *(const float4*)&feat[(size_t)i * 4];
      union { __half2 h2[2]; int2 i2; } u;
      u.h2[0] = __floats2half2_rn(v.x, v.y);
      u.h2[1] = __floats2half2_rn(v.z, v.w);
      *(int2*)&feat_h[(size_t)i * 4] = u.i2;
    }
  } else {
    int gid = (b - FEAT_B4) * 256 + tid;
    if (gid < 16384) {
      int n = gid >> 7, k = gid & 127;
      W0T[gid] = __float2half(W0[k * 128 + n]);
    } else if (gid < 32768) {
      int g = gid - 16384; int n = g >> 7, k = g & 127;
      W1T[g] = __float2half(W1[k * 128 + n]);
    } else if (gid < 40960) {
      int g = gid - 32768; int n = g >> 7, k = g & 127;   // n<64, k<128
      W2T[g] = __float2half(W2[k * 64 + n]);
    }
  }
}

// ---------------- MFMA GEMM: Y[64 x OUT] per block = X[64 x 128] @ W[128 x OUT] ----------------
// fp16 in, fp32 accum, fp16 out. WT is [n][k] (pre-transposed). LDS rows padded to 136 halves.
template <int OUT>
__global__ __launch_bounds__(256) void gemm_mfma(
    const __half* __restrict__ X, const __half* __restrict__ WT,
    __half* __restrict__ Y, int nrows) {
  constexpr int NT = OUT / 16;
  __shared__ __align__(16) __half Xs[64][136];
  __shared__ __align__(16) __half Ws[OUT][136];
  const int tid = threadIdx.x;
  const int row0 = blockIdx.x * 64;
  // stage X tile (64 x 128 halves, 16B chunks)
#pragma unroll
  for (int i = 0; i < 4; i++) {
    int ci = tid + 256 * i;            // 0..1023
    int r = ci >> 4, ch = ci & 15;
    int g = row0 + r;
    int4 v = make_int4(0, 0, 0, 0);
    if (g < nrows) v = *(const int4*)&X[(size_t)g * 128 + ch * 8];
    *(int4*)&Xs[r][ch * 8] = v;
  }
  // stage WT (OUT x 128 halves)
#pragma unroll
  for (int i = 0; i < NT; i++) {
    int ci = tid + 256 * i;            // 0..OUT*16-1
    int n = ci >> 4, ch = ci & 15;
    *(int4*)&Ws[n][ch * 8] = *(const int4*)&WT[(size_t)n * 128 + ch * 8];
  }
  __syncthreads();
  const int lane = tid & 63;
  const int w = tid >> 6;
  const int c16 = lane & 15, q = lane >> 4;
  v8h a[4];
#pragma unroll
  for (int kt = 0; kt < 4; kt++)
    a[kt] = *(const v8h*)&Xs[w * 16 + c16][kt * 32 + q * 8];
  v4f acc[NT];
#pragma unroll
  for (int t = 0; t < NT; t++) acc[t] = (v4f){0.f, 0.f, 0.f, 0.f};
#pragma unroll
  for (int t = 0; t < NT; t++) {
#pragma unroll
    for (int kt = 0; kt < 4; kt++) {
      v8h bfr = *(const v8h*)&Ws[t * 16 + c16][kt * 32 + q * 8];
      acc[t] = __builtin_amdgcn_mfma_f32_16x16x32_f16(a[kt], bfr, acc[t], 0, 0, 0);
    }
  }
  // C -> LDS (wave-private rows), then cooperative coalesced fp16 store
#pragma unroll
  for (int t = 0; t < NT; t++)
#pragma unroll
    for (int r = 0; r < 4; r++)
      Xs[w * 16 + q * 4 + r][t * 16 + c16] = __float2half(acc[t][r]);
  __syncthreads();
  constexpr int OCH = OUT / 8;         // 16B chunks per row
#pragma unroll
  for (int i = 0; i < 64 * OCH / 256; i++) {
    int ci = tid + 256 * i;
    int r = ci / OCH, ch = ci % OCH;
    int g = row0 + r;
    if (g < nrows) *(int4*)&Y[(size_t)g * OUT + ch * 8] = *(const int4*)&Xs[r][ch * 8];
  }
}

// ---------------- mean aggregation (+bias, +optional LN+ReLU) -----------
// HOUT: write fp16 (GEMM input) vs fp32 (final output).
template <int F, bool LN, bool HOUT>
__global__ __launch_bounds__(256) void agg_kernel(
    const __half* __restrict__ ft,
    const int* __restrict__ row_ptr, const int* __restrict__ es,
    const float* __restrict__ bias, const float* __restrict__ g,
    const float* __restrict__ beta, void* __restrict__ out_v, int n) {
  int gw = (blockIdx.x * blockDim.x + threadIdx.x) >> 6;
  int lane = threadIdx.x & 63;
  if (gw >= n) return;
  int b = row_ptr[gw], e = row_ptr[gw + 1];
  int deg = e - b;

  constexpr int LPR = F / 8;      // lanes per row (8 halves = 16B each)
  constexpr int EW  = 64 / LPR;   // edges in flight
  const int sub = lane / LPR;
  const int ll  = lane % LPR;
  float acc[8];
#pragma unroll
  for (int q = 0; q < 8; q++) acc[q] = 0.f;

  for (int cb = b; cb < e; cb += 64) {
    int rem = e - cb; if (rem > 64) rem = 64;
    int sn_l = 0;
    if (lane < rem) sn_l = es[cb + lane];
    for (int j = 0; j < rem; j += EW) {
      int jj = j + sub;
      int sn = __shfl(sn_l, jj, 64);
      if (jj < rem) {
        union { float4 f4; __half2 h2[4]; } u;
        u.f4 = *(const float4*)&ft[(size_t)sn * F + ll * 8];
#pragma unroll
        for (int q = 0; q < 4; q++) {
          float2 f = __half22float2(u.h2[q]);
          acc[2 * q + 0] += f.x;
          acc[2 * q + 1] += f.y;
        }
      }
    }
  }

#pragma unroll
  for (int o = 32; o >= LPR; o >>= 1)
#pragma unroll
    for (int q = 0; q < 8; q++) acc[q] += __shfl_xor(acc[q], o, 64);

  float sc = (deg > 0) ? (1.0f / (float)deg) : 0.f;
  float4 b4a = *(const float4*)&bias[ll * 8 + 0];
  float4 b4b = *(const float4*)&bias[ll * 8 + 4];
  acc[0] = fmaf(acc[0], sc, b4a.x); acc[1] = fmaf(acc[1], sc, b4a.y);
  acc[2] = fmaf(acc[2], sc, b4a.z); acc[3] = fmaf(acc[3], sc, b4a.w);
  acc[4] = fmaf(acc[4], sc, b4b.x); acc[5] = fmaf(acc[5], sc, b4b.y);
  acc[6] = fmaf(acc[6], sc, b4b.z); acc[7] = fmaf(acc[7], sc, b4b.w);

  if (LN) {
    float sum = 0.f;
#pragma unroll
    for (int q = 0; q < 8; q++) sum += acc[q];
#pragma unroll
    for (int o = LPR / 2; o > 0; o >>= 1) sum += __shfl_xor(sum, o, 64);
    float mean = sum * (1.0f / 128.0f);
    float var = 0.f;
#pragma unroll
    for (int q = 0; q < 8; q++) { acc[q] -= mean; var = fmaf(acc[q], acc[q], var); }
#pragma unroll
    for (int o = LPR / 2; o > 0; o >>= 1) var += __shfl_xor(var, o, 64);
    float r = rsqrtf(var * (1.0f / 128.0f) + 1e-5f);
    float4 g4a = *(const float4*)&g[ll * 8 + 0];
    float4 g4b = *(const float4*)&g[ll * 8 + 4];
    float4 be4a = *(const float4*)&beta[ll * 8 + 0];
    float4 be4b = *(const float4*)&beta[ll * 8 + 4];
#pragma unroll
    for (int q = 0; q < 8; q++) acc[q] *= r;
    acc[0] = fmaxf(acc[0] * g4a.x + be4a.x, 0.f);
    acc[1] = fmaxf(acc[1] * g4a.y + be4a.y, 0.f);
    acc[2] = fmaxf(acc[2] * g4a.z + be4a.z, 0.f);
    acc[3] = fmaxf(acc[3] * g4a.w + be4a.w, 0.f);
    acc[4] = fmaxf(acc[4] * g4b.x + be4b.x, 0.f);
    acc[5] = fmaxf(acc[5] * g4b.y + be4b.y, 0.f);
    acc[6] = fmaxf(acc[6] * g4b.z + be4b.z, 0.f);
    acc[7] = fmaxf(acc[7] * g4b.w + be4b.w, 0.f);
  }
  if (sub == 0) {
    if (HOUT) {
      __half* outh = (__half*)out_v;
      union { __half2 h2[4]; int4 i4; } u;
      u.h2[0] = __floats2half2_rn(acc[0], acc[1]);
      u.h2[1] = __floats2half2_rn(acc[2], acc[3]);
      u.h2[2] = __floats2half2_rn(acc[4], acc[5]);
      u.h2[3] = __floats2half2_rn(acc[6], acc[7]);
      *(int4*)&outh[(size_t)gw * F + ll * 8] = u.i4;
    } else {
      float* outf = (float*)out_v;
      *(float4*)&outf[(size_t)gw * F + ll * 8 + 0] = make_float4(acc[0], acc[1], acc[2], acc[3]);
      *(float4*)&outf[(size_t)gw * F + ll * 8 + 4] = make_float4(acc[4], acc[5], acc[6], acc[7]);
    }
  }
}

// ---------------- bucketed CSR build (proven R8 structure) ----------------
__global__ __launch_bounds__(256) void bhist_kernel(const int* __restrict__ dst,
                                                    int* __restrict__ bhist) {
  __shared__ int hh[256];
  int tid = threadIdx.x;
  hh[tid] = 0;
  __syncthreads();
#pragma unroll
  for (int q = 0; q < 4; q++) {
    int base = blockIdx.x * STILE + q * 1024 + tid * 4;
    if (base + 3 < NE) {
      int4 d = *(const int4*)&dst[base];
      atomicAdd(&hh[d.x >> 8], 1);
      atomicAdd(&hh[d.y >> 8], 1);
      atomicAdd(&hh[d.z >> 8], 1);
      atomicAdd(&hh[d.w >> 8], 1);
    } else {
#pragma unroll
      for (int k = 0; k < 4; k++)
        if (base + k < NE) atomicAdd(&hh[dst[base + k] >> 8], 1);
    }
  }
  __syncthreads();
  if (tid < NB && hh[tid]) atomicAdd(&bhist[tid * CPAD], hh[tid]);
}

__global__ __launch_bounds__(256) void bscan_kernel(const int* __restrict__ bhist,
                                                    int* __restrict__ bucket_base,
                                                    int* __restrict__ bfill) {
  int tid = threadIdx.x;
  int lane = tid & 63, wid = tid >> 6;
  int v = (tid < NB) ? bhist[tid * CPAD] : 0;
  int x = v;
#pragma unroll
  for (int o = 1; o < 64; o <<= 1) {
    int y = __shfl_up(x, o, 64);
    if (lane >= o) x += y;
  }
  __shared__ int wsum[4];
  if (lane == 63) wsum[wid] = x;
  __syncthreads();
  int wpre = 0;
  for (int w = 0; w < wid; w++) wpre += wsum[w];
  int excl = wpre + x - v;
  if (tid < NB) {
    bucket_base[tid] = excl;
    bfill[tid * CPAD] = excl;
  }
  if (tid == 0) bucket_base[NB] = NE;
}

__global__ __launch_bounds__(256) void stage_kernel(const int* __restrict__ src,
                                                    const int* __restrict__ dst,
                                                    int* __restrict__ bfill,
                                                    int* __restrict__ staged) {
  __shared__ int cnt[256];
  __shared__ int basep[256];
  __shared__ int cur[256];
  int tid = threadIdx.x;
  cnt[tid] = 0;
  cur[tid] = 0;
  __syncthreads();
#pragma unroll
  for (int q = 0; q < 4; q++) {
    int base = blockIdx.x * STILE + q * 1024 + tid * 4;
    if (base + 3 < NE) {
      int4 d = *(const int4*)&dst[base];
      atomicAdd(&cnt[d.x >> 8], 1);
      atomicAdd(&cnt[d.y >> 8], 1);
      atomicAdd(&cnt[d.z >> 8], 1);
      atomicAdd(&cnt[d.w >> 8], 1);
    } else {
#pragma unroll
      for (int k = 0; k < 4; k++)
        if (base + k < NE) atomicAdd(&cnt[dst[base + k] >> 8], 1);
    }
  }
  __syncthreads();
  if (tid < NB) basep[tid] = (cnt[tid] > 0) ? atomicAdd(&bfill[tid * CPAD], cnt[tid]) : 0;
  __syncthreads();
#pragma unroll
  for (int q = 0; q < 4; q++) {
    int base = blockIdx.x * STILE + q * 1024 + tid * 4;
    if (base + 3 < NE) {
      int4 d = *(const int4*)&dst[base];
      int4 s = *(const int4*)&src[base];
      int b0 = d.x >> 8, b1 = d.y >> 8, b2 = d.z >> 8, b3 = d.w >> 8;
      int p0 = atomicAdd(&cur[b0], 1);
      staged[basep[b0] + p0] = s.x | ((d.x & 255) << 16);
      int p1 = atomicAdd(&cur[b1], 1);
      staged[basep[b1] + p1] = s.y | ((d.y & 255) << 16);
      int p2 = atomicAdd(&cur[b2], 1);
      staged[basep[b2] + p2] = s.z | ((d.z & 255) << 16);
      int p3 = atomicAdd(&cur[b3], 1);
      staged[basep[b3] + p3] = s.w | ((d.w & 255) << 16);
    } else {
#pragma unroll
      for (int k = 0; k < 4; k++) {
        if (base + k < NE) {
          int d = dst[base + k], s = src[base + k];
          int bb = d >> 8;
          int pp = atomicAdd(&cur[bb], 1);
          staged[basep[bb] + pp] = s | ((d & 255) << 16);
        }
      }
    }
  }
}

__global__ __launch_bounds__(256) void bucket_csr_kernel(const int* __restrict__ staged,
                                                         const int* __restrict__ bucket_base,
                                                         int* __restrict__ row_ptr,
                                                         int* __restrict__ es) {
  int b = blockIdx.x;
  int tid = threadIdx.x;
  int lo = bucket_base[b], hi = bucket_base[b + 1];
  __shared__ int cnt[256];
  __shared__ int fill_l[256];
  __shared__ int wsum[4];
  cnt[tid] = 0;
  __syncthreads();
  for (int i = lo + tid; i < hi; i += 256)
    atomicAdd(&cnt[(staged[i] >> 16) & 255], 1);
  __syncthreads();
  int v = cnt[tid];
  int lane = tid & 63, wid = tid >> 6;
  int x = v;
#pragma unroll
  for (int o = 1; o < 64; o <<= 1) {
    int y = __shfl_up(x, o, 64);
    if (lane >= o) x += y;
  }
  if (lane == 63) wsum[wid] = x;
  __syncthreads();
  int wpre = 0;
  for (int w = 0; w < wid; w++) wpre += wsum[w];
  int start = lo + wpre + x - v;
  int node = (b << 8) + tid;
  if (node < NN) row_ptr[node] = start;
  fill_l[tid] = start;
  __syncthreads();
  for (int i = lo + tid; i < hi; i += 256) {
    int w = staged[i];
    int pos = atomicAdd(&fill_l[(w >> 16) & 255], 1);
    es[pos] = w & 0xFFFF;
  }
  if (b == 0 && tid == 0) row_ptr[NN] = NE;
}

// ---------------- orchestration ----------------
extern "C" void kernel_launch(void* const* d_in, const int* in_sizes, int n_in,
                              void* d_out, int out_size, void* d_ws, size_t ws_size,
                              hipStream_t stream) {
  (void)in_sizes; (void)n_in; (void)out_size; (void)ws_size;
  const float* feat = (const float*)d_in[0];
  const int* src = (const int*)d_in[1];
  const int* dst = (const int*)d_in[2];
  const float* W0 = (const float*)d_in[3];
  const float* b0 = (const float*)d_in[4];
  const float* W1 = (const float*)d_in[5];
  const float* b1 = (const float*)d_in[6];
  const float* W2 = (const float*)d_in[7];
  const float* b2 = (const float*)d_in[8];
  const float* ln1g = (const float*)d_in[9];
  const float* ln1b = (const float*)d_in[10];
  const float* ln2g = (const float*)d_in[11];
  const float* ln2b = (const float*)d_in[12];
  float* out = (float*)d_out;

  char* p = (char*)d_ws;
  auto alloc = [&](size_t bytes) {
    char* r = p;
    p += (bytes + 255) & ~size_t(255);
    return r;
  };
  __half* fth      = (__half*)alloc((size_t)NN * 128 * 2);
  __half* hh       = (__half*)alloc((size_t)NN * 128 * 2);
  __half* feat_h   = (__half*)alloc((size_t)NN * 128 * 2);
  __half* W0T      = (__half*)alloc(128 * 128 * 2);
  __half* W1T      = (__half*)alloc(128 * 128 * 2);
  __half* W2T      = (__half*)alloc(64 * 128 * 2);
  int* row_ptr     = (int*)alloc((size_t)(NN + 1) * 4);
  int* es          = (int*)alloc((size_t)NE * 4);
  int* staged      = (int*)alloc((size_t)NE * 4);
  int* bhist       = (int*)alloc((size_t)NB * CPAD * 4);
  int* bfill       = (int*)alloc((size_t)NB * CPAD * 4);
  int* bucket_base = (int*)alloc((size_t)(NB + 1) * 4);

  // CSR by dst (graph identical for all 3 convs)
  hipMemsetAsync(bhist, 0, (size_t)NB * CPAD * 4, stream);
  int sb = (NE + STILE - 1) / STILE;   // 196 blocks
  bhist_kernel<<<sb, 256, 0, stream>>>(dst, bhist);
  bscan_kernel<<<1, 256, 0, stream>>>(bhist, bucket_base, bfill);
  stage_kernel<<<sb, 256, 0, stream>>>(src, dst, bfill, staged);
  bucket_csr_kernel<<<NB, 256, 0, stream>>>(staged, bucket_base, row_ptr, es);

  // fp16 conversions (feat + transposed weights)
  convert_kernel<<<FEAT_B4 + 160, 256, 0, stream>>>(feat, W0, W1, W2, feat_h, W0T, W1T, W2T);

  int gb = (NN + 63) / 64;     // 782
  int nwb = (NN + 3) / 4;

  gemm_mfma<128><<<gb, 256, 0, stream>>>(feat_h, W0T, fth, NN);
  agg_kernel<128, true, true><<<nwb, 256, 0, stream>>>(fth, row_ptr, es, b0, ln1g, ln1b, hh, NN);
  gemm_mfma<128><<<gb, 256, 0, stream>>>(hh, W1T, fth, NN);
  agg_kernel<128, true, true><<<nwb, 256, 0, stream>>>(fth, row_ptr, es, b1, ln2g, ln2b, hh, NN);
  gemm_mfma<64><<<gb, 256, 0, stream>>>(hh, W2T, fth, NN);
  agg_kernel<64, false, false><<<nwb, 256, 0, stream>>>(fth, row_ptr, es, b2, nullptr, nullptr, out, NN);
}